// Round 1
// 130.521 us; speedup vs baseline: 1.0180x; 1.0180x over previous
//
#include <hip/hip_runtime.h>
#include <hip/hip_fp16.h>

// Problem constants (match reference)
#define BB 8
#define NN 1024
#define IN_DIM 512
#define HH 8
#define SUP 64
#define HS (HH * SUP)   // 512

// LDS row strides in halves. MUST be a multiple of 8 halves (16 B) so
// half8 LDS accesses stay b128 (R8 lesson: stride 34 split them into b32,
// -7.5us). 40 measured best for k1 (R7).
#define XS_STRIDE 40
// k2 full-resident V^T stride: 1024+8 halves. Row stride 2064 B = 516 dw
// == 4 banks (mod 32) -> identical read-conflict geometry to the tuned
// VT_STRIDE=136 (272 B == 4 banks) of the per-tile version.
#define VT2 1032

typedef _Float16 half8 __attribute__((ext_vector_type(8)));
typedef _Float16 half2v __attribute__((ext_vector_type(2)));
typedef float floatx4 __attribute__((ext_vector_type(4)));

// ---------------------------------------------------------------------------
// kW: W[h][i][o] fp32 -> Wt[h][o][i] fp16 (transpose + downconvert).
// grid 64, block 256.
// ---------------------------------------------------------------------------
__global__ __launch_bounds__(256) void kW(const float* __restrict__ W,
                                          _Float16* __restrict__ Wt) {
    __shared__ float tile[64][65];
    const int it = blockIdx.x & 7;
    const int h  = blockIdx.x >> 3;
    const int t  = threadIdx.x;
    {
        const int i  = t >> 2;
        const int o0 = (t & 3) * 16;
        const float* src = W + ((size_t)h * IN_DIM + it * 64 + i) * SUP + o0;
#pragma unroll
        for (int j = 0; j < 4; j++) {
            float4 v = ((const float4*)src)[j];
            tile[i][o0 + j * 4 + 0] = v.x;
            tile[i][o0 + j * 4 + 1] = v.y;
            tile[i][o0 + j * 4 + 2] = v.z;
            tile[i][o0 + j * 4 + 3] = v.w;
        }
    }
    __syncthreads();
    {
        const int o  = t >> 2;
        const int i0 = (t & 3) * 16;
        _Float16 buf[16];
#pragma unroll
        for (int j = 0; j < 16; j++) buf[j] = (_Float16)tile[i0 + j][o];
        _Float16* dst = Wt + ((size_t)h * SUP + o) * IN_DIM + it * 64 + i0;
        *(half8*)dst       = *(half8*)buf;
        *(half8*)(dst + 8) = *(half8*)(buf + 8);
    }
}

// ---------------------------------------------------------------------------
// k1: 1-D grid, XCD-swizzled.
//   bid < 512: projection, TWO heads per block. flat-id ≡ b (mod 8) so all
//     64 blocks sharing batch b land on one XCD -> X slab (2 MB) is L2-hot.
//     b = bid&7, j = bid>>3, hp = j&3, tile = j>>2.
//   bid >= 512: pack A fp32 (0/1) -> bitmask Am[row][128 B] (ballot).
// grid 768, block 256 (4 waves).
// ---------------------------------------------------------------------------
__global__ __launch_bounds__(256) void k1_proj(const float* __restrict__ X,
                                               const _Float16* __restrict__ Wt,
                                               const float* __restrict__ A,
                                               unsigned char* __restrict__ Am,
                                               const float* __restrict__ w1,
                                               const float* __restrict__ b1,
                                               const float* __restrict__ w2,
                                               const float* __restrict__ b2,
                                               _Float16* __restrict__ Pt,
                                               float* __restrict__ s_g,
                                               float* __restrict__ t_g,
                                               float* __restrict__ tmax16) {
    __shared__ __align__(16) _Float16 xs[2][64 * XS_STRIDE];    // X tile [n][k]
    __shared__ __align__(16) _Float16 wsh[2][128 * XS_STRIDE];  // W tile [o2][k]
    __shared__ __align__(16) _Float16 po[128 * 72];             // epilogue [o2][n]
    __shared__ float tred[2][64];

    const int bid  = blockIdx.x;
    const int t    = threadIdx.x;
    const int wave = t >> 6;
    const int lane = t & 63;

    if (bid >= 512) {
        // ---- pack A (bitmask) ----
        const int idx = bid - 512;                             // 0..255
#pragma unroll
        for (int i = 0; i < 8; i++) {
            const int row = idx * 32 + wave * 8 + i;           // 0..8191
            const float* arow = A + (size_t)row * NN;
            unsigned long long keep = 0;
#pragma unroll
            for (int g = 0; g < 16; g++) {
                float a = arow[g * 64 + lane];
                unsigned long long bal = __ballot(a > 0.5f);
                if (lane == g) keep = bal;
            }
            if (lane < 16)
                *(unsigned long long*)(Am + (size_t)row * 128 + lane * 8) = keep;
        }
        return;
    }

    // ---- projection, 2 heads; XCD-swizzled decode ----
    const int b    = bid & 7;
    const int j    = bid >> 3;         // 0..63
    const int h0   = (j & 3) * 2;
    const int bh0  = b * 8 + h0;
    const int n0   = (j >> 2) * 64;    // 16 tiles
    const int quad = lane >> 4;
    const int l15  = lane & 15;
    const int row  = t >> 2;           // X staging row 0..63
    const int koff = (t & 3) * 8;      // X staging k offset
    const int wrow  = t >> 1;          // W staging row 0..127 (2 heads)
    const int wkoff = (t & 1) * 16;    // W staging k offset

    floatx4 acc[8];
#pragma unroll
    for (int i = 0; i < 8; i++) acc[i] = {0.f, 0.f, 0.f, 0.f};

    float w1v[8], w2v[8];
#pragma unroll
    for (int ct = 0; ct < 8; ct++) {           // ct*16 spans both heads' 128 weights
        w1v[ct] = w1[h0 * 64 + ct * 16 + l15];
        w2v[ct] = w2[h0 * 64 + ct * 16 + l15];
    }
    const float b1h0 = b1[h0], b1h1 = b1[h0 + 1];
    const float b2h0 = b2[h0], b2h1 = b2[h0 + 1];

    const float*    xbase = X + ((size_t)b * NN + n0 + row) * IN_DIM + koff;
    const _Float16* wbase = Wt + ((size_t)(h0 * SUP) + wrow) * IN_DIM + wkoff;

    // prefetch slab 0
    float4 xa = ((const float4*)xbase)[0];
    float4 xb = ((const float4*)xbase)[1];
    half8  wv0 = ((const half8*)wbase)[0];
    half8  wv1 = *(const half8*)(wbase + 8);

    for (int it = 0; it < 16; it++) {
        const int cur = it & 1;
        {
            _Float16 xh[8] = {(_Float16)xa.x, (_Float16)xa.y, (_Float16)xa.z, (_Float16)xa.w,
                              (_Float16)xb.x, (_Float16)xb.y, (_Float16)xb.z, (_Float16)xb.w};
            *(half8*)&xs[cur][row * XS_STRIDE + koff] = *(half8*)xh;
            *(half8*)&wsh[cur][wrow * XS_STRIDE + wkoff]     = wv0;
            *(half8*)&wsh[cur][wrow * XS_STRIDE + wkoff + 8] = wv1;
        }
        __syncthreads();   // tile `it` visible; prior reads of buf `cur` drained
        if (it < 15) {
            const float* src = xbase + (it + 1) * 32;
            xa = ((const float4*)src)[0];
            xb = ((const float4*)src)[1];
            wv0 = *(const half8*)(wbase + (it + 1) * 32);
            wv1 = *(const half8*)(wbase + (it + 1) * 32 + 8);
        }
        half8 af = *(const half8*)&xs[cur][(wave * 16 + l15) * XS_STRIDE + quad * 8];
#pragma unroll
        for (int ct = 0; ct < 8; ct++) {
            half8 bf = *(const half8*)&wsh[cur][(ct * 16 + l15) * XS_STRIDE + quad * 8];
            acc[ct] = __builtin_amdgcn_mfma_f32_16x16x32_f16(af, bf, acc[ct], 0, 0, 0);
        }
        // no second barrier: next write goes to the other buffer
    }
    __syncthreads();

    // epilogue 1: po[o2][n] fp16 tile + s/t for both heads
#pragma unroll
    for (int ct = 0; ct < 8; ct++) {
#pragma unroll
        for (int r = 0; r < 4; r++) {
            int o = ct * 16 + l15;                 // 0..127
            int n = wave * 16 + quad * 4 + r;
            po[o * 72 + n] = (_Float16)acc[ct][r];
        }
    }
#pragma unroll
    for (int r = 0; r < 4; r++) {
        float sp0 = 0.f, tp0 = 0.f, sp1 = 0.f, tp1 = 0.f;
#pragma unroll
        for (int ct = 0; ct < 4; ct++) {
            sp0 += acc[ct][r] * w1v[ct];
            tp0 += acc[ct][r] * w2v[ct];
            sp1 += acc[ct + 4][r] * w1v[ct + 4];
            tp1 += acc[ct + 4][r] * w2v[ct + 4];
        }
#pragma unroll
        for (int off = 1; off < 16; off <<= 1) {
            sp0 += __shfl_xor(sp0, off);
            tp0 += __shfl_xor(tp0, off);
            sp1 += __shfl_xor(sp1, off);
            tp1 += __shfl_xor(tp1, off);
        }
        if (l15 == 0) {
            const int n = wave * 16 + quad * 4 + r;
            s_g[(size_t)bh0 * NN + n0 + n] = sp0 + b1h0;
            float tv0 = tp0 + b2h0;
            t_g[(size_t)bh0 * NN + n0 + n] = tv0;
            tred[0][n] = tv0;
            s_g[(size_t)(bh0 + 1) * NN + n0 + n] = sp1 + b1h1;
            float tv1 = tp1 + b2h1;
            t_g[(size_t)(bh0 + 1) * NN + n0 + n] = tv1;
            tred[1][n] = tv1;
        }
    }
    __syncthreads();
    // epilogue 2: coalesced Pt store (both heads; flat index bh0*64 + orow)
    {
        const int orow = t >> 1;          // 0..127
        const int nof  = (t & 1) * 32;
        _Float16* dst = Pt + ((size_t)(bh0 * SUP + orow)) * NN + n0 + nof;
        const _Float16* src = &po[orow * 72 + nof];
        *(half8*)dst        = *(const half8*)src;
        *(half8*)(dst + 8)  = *(const half8*)(src + 8);
        *(half8*)(dst + 16) = *(const half8*)(src + 16);
        *(half8*)(dst + 24) = *(const half8*)(src + 24);
    }
    if (t == 0) {
        float m0 = -1e30f, m1 = -1e30f;
#pragma unroll
        for (int i = 0; i < 64; i++) {
            m0 = fmaxf(m0, tred[0][i]);
            m1 = fmaxf(m1, tred[1][i]);
        }
        tmax16[bh0 * 16 + (n0 >> 6)] = m0;
        tmax16[(bh0 + 1) * 16 + (n0 >> 6)] = m1;
    }
}

// ---------------------------------------------------------------------------
// k2: fused masked-softmax attention + aggregation, packed-fp16 logit math.
// RESTRUCTURED (this round): full V^T slab resident in LDS (129 KiB),
// ONE barrier total, no per-tile staging/double-buffer. 256 blocks x 1024
// threads = 1 block/CU (16 waves = 4/SIMD), 256 query rows per block.
// XCD swizzle: flat-id ≡ b (mod 8) so each XCD keeps Am[b] (128 KB) AND
// Pt[b,*] (1 MB) L2-resident. Main loop is pure LDS+VALU+MFMA with
// register-prefetched mask words -> compiler can pipeline across mt.
// ---------------------------------------------------------------------------
__global__ __launch_bounds__(1024) void k2_attn(const unsigned char* __restrict__ Am,
                                                const _Float16* __restrict__ Pt,
                                                const float* __restrict__ s_g,
                                                const float* __restrict__ t_g,
                                                const float* __restrict__ tmax16,
                                                float* __restrict__ out) {
    __shared__ __align__(16) _Float16 vts[64 * VT2];           // V^T [o][m] 132096 B
    __shared__ __align__(16) unsigned t2l[NN / 2];             // t as packed half2 (2 KB)
    __shared__ __align__(16) uint4 lutm[256];                  // bit->fp16-mask LUT (4 KB)

    const int bid  = blockIdx.x;
    const int b    = bid & 7;          // XCD id -> Am[b] + Pt[b,*] L2-hot
    const int rest = bid >> 3;         // 0..31
    const int h    = rest & 7;
    const int bh   = b * 8 + h;
    const int n0   = (rest >> 3) * 256;  // 4 tiles of 256 query rows
    const int t    = threadIdx.x;
    const int wave = t >> 6;           // 0..15
    const int lane = t & 63;
    const int quad = lane >> 4;
    const int l15  = lane & 15;

    // ---- stage the FULL V^T slab: 64 rows x 1024 halves (128 KiB) ----
    // thread t: tt=t&511 gives the tuned row4/seg pattern of the per-tile
    // version (same write bank geometry); t>>9 selects key-halves 0-511/512-1023.
    {
        const int tt   = t & 511;
        const int half = t >> 9;
        const int row4 = tt >> 3;          // 0..63 (o)
        const int seg  = tt & 7;           // 16-key segment
        const _Float16* src = Pt + ((size_t)bh * SUP + row4) * NN + half * 512 + seg * 16;
        _Float16*       dst = &vts[row4 * VT2 + half * 512 + seg * 16];
        half8 r0[4], r1[4];
#pragma unroll
        for (int m = 0; m < 4; m++) {      // 4 key-tiles of 128 within this half
            r0[m] = ((const half8*)(src + m * 128))[0];
            r1[m] = ((const half8*)(src + m * 128))[1];
        }
#pragma unroll
        for (int m = 0; m < 4; m++) {
            ((half8*)(dst + m * 128))[0] = r0[m];
            ((half8*)(dst + m * 128))[1] = r1[m];
        }
    }
    // stage t as packed fp16 pairs
    if (t < 512) {
        float2 tv2 = ((const float2*)(t_g + (size_t)bh * NN))[t];
        half2v tp = {(_Float16)tv2.x, (_Float16)tv2.y};
        t2l[t] = *(unsigned*)&tp;
    }
    // build mask-expansion LUT: byte -> 4 words of per-half 0xFFFF masks
    if (t < 256) {
        unsigned e = (unsigned)t;
        uint4 v;
        v.x = ((e & 1u)   ? 0xFFFFu : 0u) | ((e & 2u)   ? 0xFFFF0000u : 0u);
        v.y = ((e & 4u)   ? 0xFFFFu : 0u) | ((e & 8u)   ? 0xFFFF0000u : 0u);
        v.z = ((e & 16u)  ? 0xFFFFu : 0u) | ((e & 32u)  ? 0xFFFF0000u : 0u);
        v.w = ((e & 64u)  ? 0xFFFFu : 0u) | ((e & 128u) ? 0xFFFF0000u : 0u);
        lutm[t] = v;
    }

    float tmax = -1e30f;
#pragma unroll
    for (int i = 0; i < 16; i++) tmax = fmaxf(tmax, tmax16[bh * 16 + i]);

    const int myrow = wave * 16 + l15;                 // this lane's query row (0..255)
    const float sv = s_g[(size_t)bh * NN + n0 + myrow];
    const float xc = sv + tmax;
    const float cv = fmaxf(xc, 0.01f * xc);            // c >= row max logit
    const float l2e = 1.44269504f;
    const _Float16 sc1h = (_Float16)((sv - cv) * l2e);       // (s-c)*log2e
    const _Float16 sc2h = (_Float16)(-0.99f * cv * l2e);     // -0.99*c*log2e
    const half2v sc1 = {sc1h, sc1h};
    const half2v sc2 = {sc2h, sc2h};
    const half2v vl2e = {(_Float16)l2e, (_Float16)l2e};
    const half2v v001 = {(_Float16)0.01f, (_Float16)0.01f};
    const half2v ones2 = {(_Float16)1.0f, (_Float16)1.0f};

    floatx4 acc[4];
#pragma unroll
    for (int i = 0; i < 4; i++) acc[i] = {0.f, 0.f, 0.f, 0.f};
    float zp = 0.f;

    // mask row pointer + prefetch tile 0 (issued before the barrier)
    const uint4* mrow = (const uint4*)(Am + ((size_t)b * NN + n0 + myrow) * 128);
    uint4 mcur = mrow[0];

    __syncthreads();   // vts / t2l / lutm visible; ONLY barrier in the kernel

    for (int mt = 0; mt < 8; mt++) {
        uint4 mnext;
        if (mt < 7) mnext = mrow[mt + 1];
        const unsigned mw[4] = {mcur.x, mcur.y, mcur.z, mcur.w};
#pragma unroll
        for (int kk = 0; kk < 4; kk++) {
            const unsigned mbyte = (mw[kk] >> (quad * 8)) & 0xffu;
            uint4 mx = lutm[mbyte];
            const unsigned mxw[4] = {mx.x, mx.y, mx.z, mx.w};
            uint4 tw = *(const uint4*)&t2l[mt * 64 + kk * 16 + quad * 4];
            union { uint4 u; half2v h[4]; } tt; tt.u = tw;
            union { half2v h[4]; half8 h8; } wbu;
#pragma unroll
            for (int p = 0; p < 4; p++) {
                half2v y = tt.h[p] * vl2e + sc1;                    // (x-c)*log2e
                half2v w = y * v001 + sc2;                          // (.01x-c)*log2e
                half2v z = __builtin_elementwise_max(y, w);         // lrelu branch merge
                __half2 zz = *(__half2*)&z;
                __half2 ee = h2exp2(zz);                            // 2^z = e^(l-c)
                unsigned eb = (*(unsigned*)&ee) & mxw[p];           // mask
                half2v e2 = *(half2v*)&eb;
#if __has_builtin(__builtin_amdgcn_fdot2)
                zp = __builtin_amdgcn_fdot2(e2, ones2, zp, false);
#else
                zp += (float)e2.x + (float)e2.y;
#endif
                wbu.h[p] = e2;
            }
            half8 af = wbu.h8;
#pragma unroll
            for (int ct = 0; ct < 4; ct++) {
                half8 bf = *(const half8*)&vts[(ct * 16 + l15) * VT2 + mt * 128 + kk * 32 + quad * 8];
                acc[ct] = __builtin_amdgcn_mfma_f32_16x16x32_f16(af, bf, acc[ct], 0, 0, 0);
            }
        }
        if (mt < 7) mcur = mnext;
    }

    // Z reduction across quads, distribute 1/Z by shfl
    zp += __shfl_xor(zp, 16);
    zp += __shfl_xor(zp, 32);
    const float rzown = 1.0f / zp;

    // epilogue: out[b][n][h*64+o] = relu(acc / Z)
#pragma unroll
    for (int r = 0; r < 4; r++) {
        const int rr = wave * 16 + quad * 4 + r;
        const float rz = __shfl(rzown, quad * 20 + r);
#pragma unroll
        for (int ct = 0; ct < 4; ct++) {
            float v = acc[ct][r] * rz;
            v = v > 0.f ? v : 0.f;
            out[((size_t)b * NN + n0 + rr) * HS + h * SUP + ct * 16 + l15] = v;
        }
    }
}

// ---------------------------------------------------------------------------
extern "C" void kernel_launch(void* const* d_in, const int* in_sizes, int n_in,
                              void* d_out, int out_size, void* d_ws, size_t ws_size,
                              hipStream_t stream) {
    const float* A  = (const float*)d_in[0];
    const float* X  = (const float*)d_in[1];
    const float* W  = (const float*)d_in[2];
    const float* w1 = (const float*)d_in[3];
    const float* b1 = (const float*)d_in[4];
    const float* w2 = (const float*)d_in[5];
    const float* b2 = (const float*)d_in[6];
    float* out = (float*)d_out;

    char* ws = (char*)d_ws;
    _Float16*      Wt     = (_Float16*)(ws);                  // 524288 B
    _Float16*      Pt     = (_Float16*)(ws + 524288);         // 8388608 B
    float*         s_g    = (float*)(ws + 8912896);           // 262144 B
    float*         t_g    = (float*)(ws + 9175040);           // 262144 B
    float*         tmax16 = (float*)(ws + 9437184);           // 4096 B
    unsigned char* Am     = (unsigned char*)(ws + 9441280);   // 1048576 B

    hipLaunchKernelGGL(kW, dim3(64), dim3(256), 0, stream, W, Wt);
    hipLaunchKernelGGL(k1_proj, dim3(768), dim3(256), 0, stream,
                       X, Wt, A, Am, w1, b1, w2, b2, Pt, s_g, t_g, tmax16);
    hipLaunchKernelGGL(k2_attn, dim3(256), dim3(1024), 0, stream,
                       Am, Pt, s_g, t_g, tmax16, out);
}